// Round 9
// baseline (113.030 us; speedup 1.0000x reference)
//
#include <hip/hip_runtime.h>
#include <hip/hip_fp16.h>

#define NATOMS 2048
#define CCH    64
#define NE     4

#define NP    136     // #{i<=j} pairs over 16
#define K3DIM 2176    // 136*16 inflated order-3 K
#define M2B   2176
#define M1B   2312
#define KTOT  2328
#define KPAD  2336
#define NSTEP 73      // KPAD/32
#define TSS   8       // k-steps per superstep
#define NSS   10      // ceil(NSTEP/TSS)
#define MAXBS 12      // max big-slots (256 atoms each): sum ceil(cnt_e/256) <= 11

typedef _Float16 f16x8 __attribute__((ext_vector_type(8)));
typedef float f32x4 __attribute__((ext_vector_type(4)));

__host__ __device__ constexpr int pair_i(int p){ int i=0, rem=p; while (rem >= 16-i){ rem -= 16-i; ++i; } return i; }
__host__ __device__ constexpr int pair_j(int p){ int i=0, rem=p; while (rem >= 16-i){ rem -= 16-i; ++i; } return i+rem; }

template<int N> struct IC { static constexpr int value = N; };
template<int S, int E, typename F> __device__ __forceinline__ void sfor(F&& f){
  if constexpr (S < E){ f(IC<S>{}); sfor<S+1,E>(f); }
}

// monomial value for tail region (m >= M2B), compile-time M
template<int M> __device__ __forceinline__ float monval(const float (&xf)[16]){
  if constexpr (M >= KTOT) { (void)xf; return 0.f; }
  else if constexpr (M >= M1B) return xf[M - M1B];
  else {
    constexpr int p  = M - M2B;
    constexpr int i0 = pair_i(p), j0 = pair_j(p);
    return xf[i0] * xf[j0];
  }
}

template<int S, int G> __device__ __forceinline__ f16x8 tailfrag(const float (&xf)[16]){
  union { __half2 h[4]; f16x8 v; } u;
#define TE(E2) { float lo = monval<32*S+8*G+2*E2>(xf); float hi = monval<32*S+8*G+2*E2+1>(xf); \
                 u.h[E2] = __halves2half2(__float2half(lo), __float2half(hi)); }
  TE(0) TE(1) TE(2) TE(3)
#undef TE
  return u.v;
}

// ---------------- bin + usym merged ----------------
__global__ __launch_bounds__(256) void binusym_kernel(
    const int* __restrict__ types, int* counts, int* bins,
    const float* __restrict__ U3, const float* __restrict__ U2,
    const float* __restrict__ U1, float* __restrict__ Us){
  int b = blockIdx.x;
  if (b < 8){
    int n = b * 256 + threadIdx.x;
    if (n < NATOMS){
      int t = types[n];
      int pos = atomicAdd(&counts[t], 1);
      bins[t * NATOMS + pos] = n;
    }
    return;
  }
  int gid = (b - 8) * 256 + threadIdx.x;
  if (gid >= KPAD * 16 * 6) return;
  int q = gid % 6;
  int t2 = gid / 6;
  int L = t2 & 15, m = t2 >> 4;
  int w0 = q * 4;

  float v[4] = {0.f, 0.f, 0.f, 0.f};
  if (m < M2B){
    int p = m >> 4, k = m & 15;
    int i = 0, rem = p; while (rem >= 16 - i){ rem -= 16 - i; ++i; }
    int j = i + rem;
    const float* r0 = &U3[((((size_t)L*16 + i)*16 + j)*16 + k)*23];
    if (i < j){
      const float* r1 = &U3[((((size_t)L*16 + j)*16 + i)*16 + k)*23];
#pragma unroll
      for (int t = 0; t < 4; ++t){ int w = w0 + t; if (w < 23) v[t] = r0[w] + r1[w]; }
    } else {
#pragma unroll
      for (int t = 0; t < 4; ++t){ int w = w0 + t; if (w < 23) v[t] = r0[w]; }
    }
  } else if (m < M1B){
    if (w0 < 5){
      int p = m - M2B;
      int i = 0, rem = p; while (rem >= 16 - i){ rem -= 16 - i; ++i; }
      int j = i + rem;
#pragma unroll
      for (int t = 0; t < 4; ++t){
        int w = w0 + t;
        if (w < 5){
          float s = U2[(((size_t)L*16 + i)*16 + j)*5 + w];
          if (i < j) s += U2[(((size_t)L*16 + j)*16 + i)*5 + w];
          v[t] = s;
        }
      }
    }
  } else if (m < KTOT){
    if (w0 == 0){
      int i = m - M1B;
      v[0] = U1[((size_t)L*16 + i)*2 + 0];
      v[1] = U1[((size_t)L*16 + i)*2 + 1];
    }
  }
  float4* dst = (float4*)(Us + ((size_t)m*16 + L)*24 + w0);
  *dst = make_float4(v[0], v[1], v[2], v[3]);
}

// ---------------- fold: block per (s,e), all 64 channels ----------------
// Bbuf dword idx: (((e*CCH + c)*NSTEP + s)*64 + l)*4 + r ; value = half2{A(m0),A(m0+1)}
__global__ __launch_bounds__(256) void fold_kernel(
    const float* __restrict__ Us, const float* __restrict__ W3,
    const float* __restrict__ W2, const float* __restrict__ W1,
    unsigned int* __restrict__ Bbuf){
  int s = blockIdx.x, e = blockIdx.y;
  int tid = threadIdx.x;
  int l = tid >> 2, r = tid & 3, g = l >> 4, L = l & 15;
  int m0 = 32*s + 8*g + 2*r;

  __shared__ float WL[33][CCH];
  for (int t = tid; t < 33*CCH; t += 256){
    int row = t >> 6, cc = t & 63;
    float v = 0.f;
    if (row < 23)      v = W3[((size_t)e*23 + row)*CCH + cc];
    else if (row < 28) v = W2[((size_t)e*5 + (row-23))*CCH + cc];
    else if (row < 30) v = W1[((size_t)e*2 + (row-28))*CCH + cc];
    WL[row][cc] = v;
  }
  __syncthreads();

  const float4* s0 = (const float4*)(Us + ((size_t)m0*16 + L)*24);
  const float4* s1 = (const float4*)(Us + ((size_t)(m0+1)*16 + L)*24);

  const size_t ostride = (size_t)NSTEP*64*4;
  size_t obase = (((size_t)(e*CCH)*NSTEP + s)*64 + l)*4 + r;

  if (s < 68){
    float u0[24], u1[24];
#pragma unroll
    for (int q = 0; q < 6; ++q){ ((float4*)u0)[q] = s0[q]; ((float4*)u1)[q] = s1[q]; }
    for (int cc0 = 0; cc0 < CCH; cc0 += 4){
      float a0[4] = {0,0,0,0}, a1[4] = {0,0,0,0};
#pragma unroll
      for (int w = 0; w < 23; ++w){
#pragma unroll
        for (int q = 0; q < 4; ++q){
          float wv = WL[w][cc0+q];
          a0[q] += u0[w]*wv; a1[q] += u1[w]*wv;
        }
      }
#pragma unroll
      for (int q = 0; q < 4; ++q){
        union { __half2 h; unsigned int u; } hu;
        hu.h = __halves2half2(__float2half(a0[q]), __float2half(a1[q]));
        Bbuf[obase + (size_t)(cc0+q)*ostride] = hu.u;
      }
    }
  } else {
    float u0[8], u1[8];
    ((float4*)u0)[0] = s0[0]; ((float4*)u0)[1] = s0[1];
    ((float4*)u1)[0] = s1[0]; ((float4*)u1)[1] = s1[1];
    int wbase = (m0 < M1B) ? 23 : 28;
    for (int cc0 = 0; cc0 < CCH; cc0 += 4){
      float a0[4] = {0,0,0,0}, a1[4] = {0,0,0,0};
#pragma unroll
      for (int w = 0; w < 5; ++w){
#pragma unroll
        for (int q = 0; q < 4; ++q){
          float wv = WL[wbase + w][cc0+q];
          a0[q] += u0[w]*wv; a1[q] += u1[w]*wv;
        }
      }
#pragma unroll
      for (int q = 0; q < 4; ++q){
        union { __half2 h; unsigned int u; } hu;
        hu.h = __halves2half2(__float2half(a0[q]), __float2half(a1[q]));
        Bbuf[obase + (size_t)(cc0+q)*ostride] = hu.u;
      }
    }
  }
}

// ---------------- main3: 256 atoms x 1 channel per block, LDS-shared B ----------------
// grid = MAXBS*64 = 768. Bijective XCD swizzle -> 8-channel groups per XCD.
// 4 waves; wave w owns atoms [b0+64w, b0+64w+64) as 4 MFMA row-tiles.
// B staged to LDS once per block (reg->ds_write, plain barriers only).
__global__ __launch_bounds__(256, 2) void main3_kernel(
    const float* __restrict__ x, const int* __restrict__ counts,
    const int* __restrict__ bins, const uint4* __restrict__ Bbuf,
    float* __restrict__ out){
  int v = (blockIdx.x & 7) * 96 + (blockIdx.x >> 3);   // bijective for 768
  int c = v / MAXBS;
  int g = v % MAXBS;

  int c0 = counts[0], c1 = counts[1], c2 = counts[2], c3 = counts[3];
  int n0 = (c0+255)>>8, n1 = (c1+255)>>8, n2 = (c2+255)>>8, n3 = (c3+255)>>8;
  int ns = n0 + n1 + n2 + n3;
  if (g >= ns) return;
  int e, b0, cnt;
  if (g < n0){ e = 0; b0 = g*256; cnt = c0; }
  else if (g < n0+n1){ e = 1; b0 = (g-n0)*256; cnt = c1; }
  else if (g < n0+n1+n2){ e = 2; b0 = (g-n0-n1)*256; cnt = c2; }
  else { e = 3; b0 = (g-n0-n1-n2)*256; cnt = c3; }

  int wid = threadIdx.x >> 6, lane = threadIdx.x & 63;

  __shared__ uint4 lds[2][TSS*64];   // 16 KB

  // ---- x gather: 4 row-tiles per wave, all indices compile-time ----
  float xa[4][16];
#pragma unroll
  for (int T = 0; T < 4; ++T){
    int row = b0 + wid*64 + T*16 + (lane & 15);
    int n = (row < cnt) ? bins[e*NATOMS + row] : -1;
#pragma unroll
    for (int i = 0; i < 16; ++i)
      xa[T][i] = (n >= 0) ? x[((size_t)n*16 + i)*CCH + c] : 0.f;
  }

  // ---- xsel by VALUE-select (no dynamic array index -> stays in VGPRs) ----
  bool hi_half = (lane & 16) != 0;
  bool gsel    = (lane & 32) != 0;
  __half2 xsel[4][4];
#pragma unroll
  for (int T = 0; T < 4; ++T){
#pragma unroll
    for (int q = 0; q < 4; ++q){
      __half2 lo = __halves2half2(__float2half(xa[T][2*q]),   __float2half(xa[T][2*q+1]));
      __half2 hi = __halves2half2(__float2half(xa[T][8+2*q]), __float2half(xa[T][8+2*q+1]));
      xsel[T][q] = hi_half ? hi : lo;
    }
  }

  const uint4* Bpan = Bbuf + (size_t)(e*CCH + c)*NSTEP*64;

  f32x4 acc[4];
#pragma unroll
  for (int T = 0; T < 4; ++T) acc[T] = (f32x4){0.f,0.f,0.f,0.f};

  // ---- prologue: stage superstep 0 (wave w stages tiles 2w, 2w+1) ----
  {
    uint4 pa = Bpan[(size_t)(2*wid)*64 + lane];
    uint4 pb = Bpan[(size_t)(2*wid+1)*64 + lane];
    lds[0][(2*wid)*64 + lane] = pa;
    lds[0][(2*wid+1)*64 + lane] = pb;
  }
  __syncthreads();

  uint4 pf0, pf1;
  sfor<0, NSTEP>([&](auto sc){
    constexpr int s  = decltype(sc)::value;
    constexpr int ss = s / TSS;
    constexpr int k8 = s % TSS;
    constexpr int cb = ss & 1;

    if constexpr (k8 == 0 && ss + 1 < NSS){
      int t0 = (ss+1)*TSS + 2*wid;
      if (t0     < NSTEP) pf0 = Bpan[(size_t)t0*64 + lane];
      if (t0 + 1 < NSTEP) pf1 = Bpan[(size_t)(t0+1)*64 + lane];
    }

    uint4 cur = lds[cb][k8*64 + lane];

    if constexpr (32*(s+1) <= K3DIM){
      constexpr int p0 = 2*s, p1 = 2*s + 1;
      constexpr int iA = pair_i(p0), jA = pair_j(p0);
      constexpr int iB = pair_i(p1), jB = pair_j(p1);
      union { uint4 u; f16x8 v; } bc; bc.u = cur;
#pragma unroll
      for (int T = 0; T < 4; ++T){
        float pA = xa[T][iA]*xa[T][jA];
        float pB = xa[T][iB]*xa[T][jB];
        float pv = gsel ? pB : pA;
        __half2 pvh = __float2half2_rn(pv);
        union { __half2 h[4]; f16x8 v; } u;
#pragma unroll
        for (int q = 0; q < 4; ++q) u.h[q] = __hmul2(pvh, xsel[T][q]);
        acc[T] = __builtin_amdgcn_mfma_f32_16x16x32_f16(u.v, bc.v, acc[T], 0, 0, 0);
      }
    } else {
      union { uint4 u; f16x8 v; } bc; bc.u = cur;
      int gg = (lane >> 4) & 3;
#pragma unroll
      for (int T = 0; T < 4; ++T){
        f16x8 af;
        if      (gg == 0) af = tailfrag<s,0>(xa[T]);
        else if (gg == 1) af = tailfrag<s,1>(xa[T]);
        else if (gg == 2) af = tailfrag<s,2>(xa[T]);
        else              af = tailfrag<s,3>(xa[T]);
        acc[T] = __builtin_amdgcn_mfma_f32_16x16x32_f16(af, bc.v, acc[T], 0, 0, 0);
      }
    }

    if constexpr (k8 == TSS-1 || s == NSTEP-1){
      __syncthreads();
      if constexpr (ss + 1 < NSS){
        int t0 = (ss+1)*TSS + 2*wid;
        if (t0     < NSTEP) lds[(ss+1)&1][(2*wid)*64   + lane] = pf0;
        if (t0 + 1 < NSTEP) lds[(ss+1)&1][(2*wid+1)*64 + lane] = pf1;
      }
      __syncthreads();
    }
  });

  // ---- epilogue: write out ----
  int gp = lane >> 4, L = lane & 15;
#pragma unroll
  for (int T = 0; T < 4; ++T){
    int rb = b0 + wid*64 + T*16;
#pragma unroll
    for (int r = 0; r < 4; ++r){
      int row = rb + 4*gp + r;
      if (row < cnt){
        int n = bins[e*NATOMS + row];
        out[((size_t)n*16 + L)*CCH + c] = acc[T][r];
      }
    }
  }
}

// ---------------- legacy fallback (only if ws too small; known-correct) ----------------
__global__ __launch_bounds__(256) void prep_kernel(
    const float* __restrict__ U3, const float* __restrict__ U2,
    const float* __restrict__ U1, const float* __restrict__ W3,
    const float* __restrict__ W2, const float* __restrict__ W1,
    unsigned int* __restrict__ Bbuf, int CB, int CN){
  int s = blockIdx.x, e = blockIdx.y, cz = blockIdx.z;
  int tid = threadIdx.x;
  int l = tid >> 2, r = tid & 3;
  int g = l >> 4, L = l & 15;
  int m0 = 32*s + 8*g + 2*r;

  __shared__ float WL[30][16];
  {
    int cbase = CB + cz*16;
    for (int t = tid; t < 30*16; t += 256){
      int row = t >> 4, cc = t & 15;
      float v;
      if (row < 23)      v = W3[((size_t)e*23 + row)*CCH + cbase + cc];
      else if (row < 28) v = W2[((size_t)e*5 + (row-23))*CCH + cbase + cc];
      else               v = W1[((size_t)e*2 + (row-28))*CCH + cbase + cc];
      WL[row][cc] = v;
    }
  }
  __syncthreads();

  float us0[23], us1[23];
#pragma unroll
  for (int w = 0; w < 23; ++w){ us0[w] = 0.f; us1[w] = 0.f; }

  auto gather = [&](int m, float (&us)[23]) -> int {
    if (m >= KTOT) return 0;
    if (m >= M1B){
      int i = m - M1B;
#pragma unroll
      for (int w = 0; w < 2; ++w) us[w] = U1[((size_t)L*16 + i)*2 + w];
      return 1;
    }
    if (m >= M2B){
      int p = m - M2B;
      int i = 0, rem = p; while (rem >= 16-i){ rem -= 16-i; ++i; }
      int j = i + rem;
#pragma unroll
      for (int w = 0; w < 5; ++w){
        float v = U2[(((size_t)L*16 + i)*16 + j)*5 + w];
        if (i < j) v += U2[(((size_t)L*16 + j)*16 + i)*5 + w];
        us[w] = v;
      }
      return 2;
    }
    int p = m >> 4, k = m & 15;
    int i = 0, rem = p; while (rem >= 16-i){ rem -= 16-i; ++i; }
    int j = i + rem;
#pragma unroll
    for (int w = 0; w < 23; ++w){
      float v = U3[((((size_t)L*16 + i)*16 + j)*16 + k)*23 + w];
      if (i < j) v += U3[((((size_t)L*16 + j)*16 + i)*16 + k)*23 + w];
      us[w] = v;
    }
    return 3;
  };

  int cat = gather(m0, us0);
  (void)gather(m0 + 1, us1);

  for (int cc = 0; cc < 16; ++cc){
    float a0 = 0.f, a1 = 0.f;
    if (cat == 3){
#pragma unroll
      for (int w = 0; w < 23; ++w){ float wv = WL[w][cc]; a0 += us0[w]*wv; a1 += us1[w]*wv; }
    } else if (cat == 2){
#pragma unroll
      for (int w = 0; w < 5; ++w){ float wv = WL[23+w][cc]; a0 += us0[w]*wv; a1 += us1[w]*wv; }
    } else if (cat == 1){
#pragma unroll
      for (int w = 0; w < 2; ++w){ float wv = WL[28+w][cc]; a0 += us0[w]*wv; a1 += us1[w]*wv; }
    }
    union { __half2 h; unsigned int u; } hu;
    hu.h = __halves2half2(__float2half(a0), __float2half(a1));
    int cl = cz*16 + cc;
    Bbuf[(((size_t)(e*CN + cl)*NSTEP + s)*64 + l)*4 + r] = hu.u;
  }
}

__device__ __forceinline__ void gemm_body_legacy(
    const float (&xL)[16], const float (&xH)[16], const uint4* Bp,
    int lane, f32x4& accL, f32x4& accH){
  bool hi_half = (lane & 16) != 0;
  __half2 xselL[4], xselH[4];
#pragma unroll
  for (int q2 = 0; q2 < 4; ++q2){
    __half2 loL = __halves2half2(__float2half(xL[2*q2]),   __float2half(xL[2*q2+1]));
    __half2 hiL = __halves2half2(__float2half(xL[8+2*q2]), __float2half(xL[8+2*q2+1]));
    __half2 loH = __halves2half2(__float2half(xH[2*q2]),   __float2half(xH[2*q2+1]));
    __half2 hiH = __halves2half2(__float2half(xH[8+2*q2]), __float2half(xH[8+2*q2+1]));
    xselL[q2] = hi_half ? hiL : loL;
    xselH[q2] = hi_half ? hiH : loH;
  }
  bool gsel = (lane & 32) != 0;

  sfor<0, NSTEP>([&](auto sc){
    constexpr int s = decltype(sc)::value;
    uint4 cur = Bp[(size_t)s*64];

    f16x8 afL, afH;
    if constexpr (32*(s+1) <= K3DIM){
      constexpr int p0 = 2*s, p1 = 2*s + 1;
      constexpr int iA = pair_i(p0), jA = pair_j(p0);
      constexpr int iB = pair_i(p1), jB = pair_j(p1);
      float pAL = xL[iA]*xL[jA], pBL = xL[iB]*xL[jB];
      float pAH = xH[iA]*xH[jA], pBH = xH[iB]*xH[jB];
      __half2 pvL = __float2half2_rn(gsel ? pBL : pAL);
      __half2 pvH = __float2half2_rn(gsel ? pBH : pAH);
      union { __half2 h[4]; f16x8 v; } uL, uH;
#pragma unroll
      for (int q2 = 0; q2 < 4; ++q2){
        uL.h[q2] = __hmul2(pvL, xselL[q2]);
        uH.h[q2] = __hmul2(pvH, xselH[q2]);
      }
      afL = uL.v; afH = uH.v;
    } else {
      int g = (lane >> 4) & 3;
      if      (g == 0){ afL = tailfrag<s,0>(xL); afH = tailfrag<s,0>(xH); }
      else if (g == 1){ afL = tailfrag<s,1>(xL); afH = tailfrag<s,1>(xH); }
      else if (g == 2){ afL = tailfrag<s,2>(xL); afH = tailfrag<s,2>(xH); }
      else            { afL = tailfrag<s,3>(xL); afH = tailfrag<s,3>(xH); }
    }
    union { uint4 u; f16x8 v; } bc; bc.u = cur;
    accL = __builtin_amdgcn_mfma_f32_16x16x32_f16(afL, bc.v, accL, 0, 0, 0);
    accH = __builtin_amdgcn_mfma_f32_16x16x32_f16(afH, bc.v, accH, 0, 0, 0);
  });
}

__global__ __launch_bounds__(256, 2) void main_kernel(
    const float* __restrict__ x, const int* __restrict__ counts,
    const int* __restrict__ bins, const uint4* __restrict__ Bbuf,
    float* __restrict__ out, int CB, int CN){
  int lane = threadIdx.x & 63;
  int wid  = threadIdx.x >> 6;
  int d = blockIdx.x;
  int xcd = d & 7, q = d >> 3;
  int pg = q >> 4, sb = q & 15;
  int p = xcd + 8*pg;
  int e = p / CN, cl = p % CN;
  int slot = sb*4 + wid;
  int cnt = counts[e];
  if (slot * 32 >= cnt) return;
  int c = CB + cl;

  int aL = slot*32 + (lane & 15);
  int aH = aL + 16;
  int nL = (aL < cnt) ? bins[e*NATOMS + aL] : -1;
  int nH = (aH < cnt) ? bins[e*NATOMS + aH] : -1;

  float xL[16], xH[16];
#pragma unroll
  for (int i = 0; i < 16; ++i){
    xL[i] = (nL >= 0) ? x[((size_t)nL*16 + i)*CCH + c] : 0.f;
    xH[i] = (nH >= 0) ? x[((size_t)nH*16 + i)*CCH + c] : 0.f;
  }

  const uint4* Bp = Bbuf + ((size_t)(e*CN + cl))*NSTEP*64 + lane;
  f32x4 accL = {0.f,0.f,0.f,0.f}, accH = {0.f,0.f,0.f,0.f};
  gemm_body_legacy(xL, xH, Bp, lane, accL, accH);

  int gp = lane >> 4, L = lane & 15;
#pragma unroll
  for (int r = 0; r < 4; ++r){
    int pl = slot*32 + 4*gp + r;
    if (pl < cnt){ int n = bins[e*NATOMS + pl]; out[((size_t)n*16 + L)*CCH + c] = accL[r]; }
    int ph = pl + 16;
    if (ph < cnt){ int n = bins[e*NATOMS + ph]; out[((size_t)n*16 + L)*CCH + c] = accH[r]; }
  }
}

extern "C" void kernel_launch(void* const* d_in, const int* in_sizes, int n_in,
                              void* d_out, int out_size, void* d_ws, size_t ws_size,
                              hipStream_t stream){
  const float* x   = (const float*)d_in[0];
  const int* types = (const int*)d_in[1];
  const float* U3  = (const float*)d_in[2];
  const float* U2  = (const float*)d_in[3];
  const float* U1  = (const float*)d_in[4];
  const float* W3  = (const float*)d_in[5];
  const float* W2  = (const float*)d_in[6];
  const float* W1  = (const float*)d_in[7];
  float* out = (float*)d_out;

  char* ws = (char*)d_ws;
  int* counts  = (int*)ws;               // +0    (16 B)
  int* bins    = (int*)(ws + 1024);      // +1024 (32 KB) -> ends 33792

  const size_t usOff   = 33792;                               // 512-aligned
  const size_t usBytes = (size_t)KPAD * 16 * 24 * 4;          // 3,588,096
  const size_t bbOff   = usOff + usBytes;                     // 3,621,888 (512-aligned)
  const size_t bbBytes = (size_t)NE * 64 * NSTEP * 64 * 16;   // 19,136,512

  hipMemsetAsync(counts, 0, NE * sizeof(int), stream);

  if (ws_size >= bbOff + bbBytes){
    float* Us = (float*)(ws + usOff);
    unsigned int* Bbuf = (unsigned int*)(ws + bbOff);
    int usymBlocks = (KPAD*16*6 + 255)/256;
    binusym_kernel<<<8 + usymBlocks, 256, 0, stream>>>(types, counts, bins, U3, U2, U1, Us);
    fold_kernel<<<dim3(NSTEP, NE), 256, 0, stream>>>(Us, W3, W2, W1, Bbuf);
    main3_kernel<<<dim3(MAXBS*64), 256, 0, stream>>>(x, counts, bins, (const uint4*)Bbuf, out);
  } else if (ws_size >= 34816 + bbBytes){
    unsigned int* Bbuf = (unsigned int*)(ws + 34816);
    binusym_kernel<<<8, 256, 0, stream>>>(types, counts, bins, U3, U2, U1, (float*)(ws + usOff));
    prep_kernel<<<dim3(NSTEP, NE, 4), 256, 0, stream>>>(U3,U2,U1,W3,W2,W1,Bbuf,0,64);
    main_kernel<<<dim3(NE*64*16), 256, 0, stream>>>(x, counts, bins, (const uint4*)Bbuf, out, 0, 64);
  } else {
    unsigned int* Bbuf = (unsigned int*)(ws + 34816);
    binusym_kernel<<<8, 256, 0, stream>>>(types, counts, bins, U3, U2, U1, (float*)(ws + usOff));
    prep_kernel<<<dim3(NSTEP, NE, 2), 256, 0, stream>>>(U3,U2,U1,W3,W2,W1,Bbuf,0,32);
    main_kernel<<<dim3(NE*32*16), 256, 0, stream>>>(x, counts, bins, (const uint4*)Bbuf, out, 0, 32);
    prep_kernel<<<dim3(NSTEP, NE, 2), 256, 0, stream>>>(U3,U2,U1,W3,W2,W1,Bbuf,32,32);
    main_kernel<<<dim3(NE*32*16), 256, 0, stream>>>(x, counts, bins, (const uint4*)Bbuf, out, 32, 32);
  }
}

// Round 10
// 100.317 us; speedup vs baseline: 1.1267x; 1.1267x over previous
//
#include <hip/hip_runtime.h>
#include <hip/hip_fp16.h>

#define NATOMS 2048
#define CCH    64
#define NE     4

#define NP    136     // #{i<=j} pairs over 16
#define K3DIM 2176    // 136*16 inflated order-3 K
#define M2B   2176
#define M1B   2312
#define KTOT  2328
#define KPAD  2336
#define NSTEP 73      // KPAD/32
#define MAXBS 12      // max 256-atom slots: sum ceil(cnt_e/256) <= 11

typedef _Float16 f16x8 __attribute__((ext_vector_type(8)));
typedef float f32x4 __attribute__((ext_vector_type(4)));

__host__ __device__ constexpr int pair_i(int p){ int i=0, rem=p; while (rem >= 16-i){ rem -= 16-i; ++i; } return i; }
__host__ __device__ constexpr int pair_j(int p){ int i=0, rem=p; while (rem >= 16-i){ rem -= 16-i; ++i; } return i+rem; }

// packed order-3 pair table: step s uses pairs 2s (lanes<32) and 2s+1 (lanes>=32)
struct PTab { unsigned v[68]; };
__host__ __device__ constexpr PTab make_ptab(){
  PTab t{};
  for (int s = 0; s < 68; ++s){
    int p0 = 2*s, p1 = 2*s + 1;
    t.v[s] = (unsigned)(pair_i(p0) | (pair_j(p0)<<5) | (pair_i(p1)<<10) | (pair_j(p1)<<15));
  }
  return t;
}
__device__ __constant__ PTab ptab = make_ptab();

// ---------------- bin + usym merged ----------------
__global__ __launch_bounds__(256) void binusym_kernel(
    const int* __restrict__ types, int* counts, int* bins,
    const float* __restrict__ U3, const float* __restrict__ U2,
    const float* __restrict__ U1, float* __restrict__ Us){
  int b = blockIdx.x;
  if (b < 8){
    int n = b * 256 + threadIdx.x;
    if (n < NATOMS){
      int t = types[n];
      int pos = atomicAdd(&counts[t], 1);
      bins[t * NATOMS + pos] = n;
    }
    return;
  }
  int gid = (b - 8) * 256 + threadIdx.x;
  if (gid >= KPAD * 16 * 6) return;
  int q = gid % 6;
  int t2 = gid / 6;
  int L = t2 & 15, m = t2 >> 4;
  int w0 = q * 4;

  float v[4] = {0.f, 0.f, 0.f, 0.f};
  if (m < M2B){
    int p = m >> 4, k = m & 15;
    int i = 0, rem = p; while (rem >= 16 - i){ rem -= 16 - i; ++i; }
    int j = i + rem;
    const float* r0 = &U3[((((size_t)L*16 + i)*16 + j)*16 + k)*23];
    if (i < j){
      const float* r1 = &U3[((((size_t)L*16 + j)*16 + i)*16 + k)*23];
#pragma unroll
      for (int t = 0; t < 4; ++t){ int w = w0 + t; if (w < 23) v[t] = r0[w] + r1[w]; }
    } else {
#pragma unroll
      for (int t = 0; t < 4; ++t){ int w = w0 + t; if (w < 23) v[t] = r0[w]; }
    }
  } else if (m < M1B){
    if (w0 < 5){
      int p = m - M2B;
      int i = 0, rem = p; while (rem >= 16 - i){ rem -= 16 - i; ++i; }
      int j = i + rem;
#pragma unroll
      for (int t = 0; t < 4; ++t){
        int w = w0 + t;
        if (w < 5){
          float s = U2[(((size_t)L*16 + i)*16 + j)*5 + w];
          if (i < j) s += U2[(((size_t)L*16 + j)*16 + i)*5 + w];
          v[t] = s;
        }
      }
    }
  } else if (m < KTOT){
    if (w0 == 0){
      int i = m - M1B;
      v[0] = U1[((size_t)L*16 + i)*2 + 0];
      v[1] = U1[((size_t)L*16 + i)*2 + 1];
    }
  }
  float4* dst = (float4*)(Us + ((size_t)m*16 + L)*24 + w0);
  *dst = make_float4(v[0], v[1], v[2], v[3]);
}

// ---------------- fold: block per (s,e), all 64 channels ----------------
__global__ __launch_bounds__(256) void fold_kernel(
    const float* __restrict__ Us, const float* __restrict__ W3,
    const float* __restrict__ W2, const float* __restrict__ W1,
    unsigned int* __restrict__ Bbuf){
  int s = blockIdx.x, e = blockIdx.y;
  int tid = threadIdx.x;
  int l = tid >> 2, r = tid & 3, g = l >> 4, L = l & 15;
  int m0 = 32*s + 8*g + 2*r;

  __shared__ float WL[33][CCH];
  for (int t = tid; t < 33*CCH; t += 256){
    int row = t >> 6, cc = t & 63;
    float v = 0.f;
    if (row < 23)      v = W3[((size_t)e*23 + row)*CCH + cc];
    else if (row < 28) v = W2[((size_t)e*5 + (row-23))*CCH + cc];
    else if (row < 30) v = W1[((size_t)e*2 + (row-28))*CCH + cc];
    WL[row][cc] = v;
  }
  __syncthreads();

  const float4* s0 = (const float4*)(Us + ((size_t)m0*16 + L)*24);
  const float4* s1 = (const float4*)(Us + ((size_t)(m0+1)*16 + L)*24);

  const size_t ostride = (size_t)NSTEP*64*4;
  size_t obase = (((size_t)(e*CCH)*NSTEP + s)*64 + l)*4 + r;

  if (s < 68){
    float u0[24], u1[24];
#pragma unroll
    for (int q = 0; q < 6; ++q){ ((float4*)u0)[q] = s0[q]; ((float4*)u1)[q] = s1[q]; }
    for (int cc0 = 0; cc0 < CCH; cc0 += 4){
      float a0[4] = {0,0,0,0}, a1[4] = {0,0,0,0};
#pragma unroll
      for (int w = 0; w < 23; ++w){
#pragma unroll
        for (int q = 0; q < 4; ++q){
          float wv = WL[w][cc0+q];
          a0[q] += u0[w]*wv; a1[q] += u1[w]*wv;
        }
      }
#pragma unroll
      for (int q = 0; q < 4; ++q){
        union { __half2 h; unsigned int u; } hu;
        hu.h = __halves2half2(__float2half(a0[q]), __float2half(a1[q]));
        Bbuf[obase + (size_t)(cc0+q)*ostride] = hu.u;
      }
    }
  } else {
    float u0[8], u1[8];
    ((float4*)u0)[0] = s0[0]; ((float4*)u0)[1] = s0[1];
    ((float4*)u1)[0] = s1[0]; ((float4*)u1)[1] = s1[1];
    int wbase = (m0 < M1B) ? 23 : 28;
    for (int cc0 = 0; cc0 < CCH; cc0 += 4){
      float a0[4] = {0,0,0,0}, a1[4] = {0,0,0,0};
#pragma unroll
      for (int w = 0; w < 5; ++w){
#pragma unroll
        for (int q = 0; q < 4; ++q){
          float wv = WL[wbase + w][cc0+q];
          a0[q] += u0[w]*wv; a1[q] += u1[w]*wv;
        }
      }
#pragma unroll
      for (int q = 0; q < 4; ++q){
        union { __half2 h; unsigned int u; } hu;
        hu.h = __halves2half2(__float2half(a0[q]), __float2half(a1[q]));
        Bbuf[obase + (size_t)(cc0+q)*ostride] = hu.u;
      }
    }
  }
}

// ---------------- main4: runtime-looped MFMA GEMM, tiny code footprint ----------------
// 256 atoms x 1 channel per block; 4 waves x 4 row-tiles; x rows in LDS (f16, dynamic
// index legal); order-3 pair indices from constexpr scalar table; B double-buffered
// in LDS per 4-step superstep.
__global__ __launch_bounds__(256, 3) void main4_kernel(
    const float* __restrict__ x, const int* __restrict__ counts,
    const int* __restrict__ bins, const uint4* __restrict__ Bbuf,
    float* __restrict__ out){
  int v = (blockIdx.x & 7) * 96 + (blockIdx.x >> 3);   // bijective for 768
  int c = v / MAXBS;
  int g = v % MAXBS;

  int c0 = counts[0], c1 = counts[1], c2 = counts[2], c3 = counts[3];
  int n0 = (c0+255)>>8, n1 = (c1+255)>>8, n2 = (c2+255)>>8, n3 = (c3+255)>>8;
  int ns = n0 + n1 + n2 + n3;
  if (g >= ns) return;
  int e, b0, cnt;
  if (g < n0){ e = 0; b0 = g*256; cnt = c0; }
  else if (g < n0+n1){ e = 1; b0 = (g-n0)*256; cnt = c1; }
  else if (g < n0+n1+n2){ e = 2; b0 = (g-n0-n1)*256; cnt = c2; }
  else { e = 3; b0 = (g-n0-n1-n2)*256; cnt = c3; }

  int tid = threadIdx.x;
  int wid = tid >> 6, lane = tid & 63;

  __shared__ __half xe[4][256][18];      // 36,864 B ; [T][tid][i], i16=1.0, i17=0.0
  __shared__ uint4  bsm[2][256];         //  8,192 B ; double-buffered B (4 tiles each)
  __shared__ unsigned ltab[160];         //    640 B ; tail element (i,j) table

  // ---- init: x gather (static indices), xsel build, xe/ltab fill ----
  float xa[4][16];
#pragma unroll
  for (int T = 0; T < 4; ++T){
    int row = b0 + wid*64 + T*16 + (lane & 15);
    int n = (row < cnt) ? bins[e*NATOMS + row] : -1;
#pragma unroll
    for (int i = 0; i < 16; ++i)
      xa[T][i] = (n >= 0) ? x[((size_t)n*16 + i)*CCH + c] : 0.f;
  }

  bool hi_half = (lane & 16) != 0;
  bool gsel    = (lane & 32) != 0;
  __half2 xsel[4][4];
#pragma unroll
  for (int T = 0; T < 4; ++T){
#pragma unroll
    for (int q = 0; q < 4; ++q){
      __half2 lo = __halves2half2(__float2half(xa[T][2*q]),   __float2half(xa[T][2*q+1]));
      __half2 hi = __halves2half2(__float2half(xa[T][8+2*q]), __float2half(xa[T][8+2*q+1]));
      xsel[T][q] = hi_half ? hi : lo;
    }
  }

#pragma unroll
  for (int T = 0; T < 4; ++T){
#pragma unroll
    for (int i = 0; i < 16; ++i) xe[T][tid][i] = __float2half(xa[T][i]);
    xe[T][tid][16] = __float2half(1.0f);
    xe[T][tid][17] = __float2half(0.0f);
  }

  if (tid < 160){
    unsigned ij;
    if (tid < NP)        ij = (unsigned)(pair_i(tid) | (pair_j(tid) << 8));
    else if (tid < 152)  ij = (unsigned)((tid - NP) | (16 << 8));   // linear: x_i * 1
    else                 ij = (unsigned)(17 | (17 << 8));           // pad: 0 * 0
    ltab[tid] = ij;
  }

  const uint4* Bpan = Bbuf + (size_t)(e*CCH + c)*NSTEP*64;
  bsm[0][tid] = Bpan[tid];               // stage tiles 0..3
  __syncthreads();

  f32x4 acc0 = {0,0,0,0}, acc1 = {0,0,0,0}, acc2 = {0,0,0,0}, acc3 = {0,0,0,0};

  // ---- order-3 main loop: 17 supersteps x 4 steps, runtime-looped ----
  for (int ss = 0; ss < 17; ++ss){
    uint4 pf = Bpan[(ss+1)*256 + tid];   // tiles 4ss+4 .. 4ss+7 (always in range: <=4607)
    int cb = ss & 1;
    for (int k = 0; k < 4; ++k){
      uint4 cur = bsm[cb][k*64 + lane];
      unsigned pk = ptab.v[ss*4 + k];    // wave-uniform -> scalar load
      int iA = pk & 31, jA = (pk>>5) & 31, iB = (pk>>10) & 31, jB = (pk>>15) & 31;
      int isel = gsel ? iB : iA;
      int jsel = gsel ? jB : jA;
      union { uint4 u; f16x8 h; } bc; bc.u = cur;
#pragma unroll
      for (int T = 0; T < 4; ++T){
        __half p = __hmul(xe[T][tid][isel], xe[T][tid][jsel]);
        __half2 pv = __half2half2(p);
        union { __half2 h[4]; f16x8 v; } u;
#pragma unroll
        for (int q = 0; q < 4; ++q) u.h[q] = __hmul2(pv, xsel[T][q]);
        if      (T == 0) acc0 = __builtin_amdgcn_mfma_f32_16x16x32_f16(u.v, bc.h, acc0, 0,0,0);
        else if (T == 1) acc1 = __builtin_amdgcn_mfma_f32_16x16x32_f16(u.v, bc.h, acc1, 0,0,0);
        else if (T == 2) acc2 = __builtin_amdgcn_mfma_f32_16x16x32_f16(u.v, bc.h, acc2, 0,0,0);
        else             acc3 = __builtin_amdgcn_mfma_f32_16x16x32_f16(u.v, bc.h, acc3, 0,0,0);
      }
    }
    __syncthreads();
    bsm[cb ^ 1][tid] = pf;
    __syncthreads();
  }

  // ---- tail: steps 68..72 via element table (runtime loop) ----
  int g2 = (lane >> 4) & 3;
  auto tail_step = [&](int s, uint4 cur){
    int mb = 32*s + 8*g2 - M2B;          // ltab base, in [0,160)
    unsigned t0 = ltab[mb+0], t1 = ltab[mb+1], t2 = ltab[mb+2], t3 = ltab[mb+3];
    unsigned t4 = ltab[mb+4], t5 = ltab[mb+5], t6 = ltab[mb+6], t7 = ltab[mb+7];
    union { uint4 u; f16x8 h; } bc; bc.u = cur;
#pragma unroll
    for (int T = 0; T < 4; ++T){
      union { __half2 h[4]; f16x8 v; } u;
      u.h[0] = __halves2half2(__hmul(xe[T][tid][t0 & 255], xe[T][tid][t0 >> 8]),
                              __hmul(xe[T][tid][t1 & 255], xe[T][tid][t1 >> 8]));
      u.h[1] = __halves2half2(__hmul(xe[T][tid][t2 & 255], xe[T][tid][t2 >> 8]),
                              __hmul(xe[T][tid][t3 & 255], xe[T][tid][t3 >> 8]));
      u.h[2] = __halves2half2(__hmul(xe[T][tid][t4 & 255], xe[T][tid][t4 >> 8]),
                              __hmul(xe[T][tid][t5 & 255], xe[T][tid][t5 >> 8]));
      u.h[3] = __halves2half2(__hmul(xe[T][tid][t6 & 255], xe[T][tid][t6 >> 8]),
                              __hmul(xe[T][tid][t7 & 255], xe[T][tid][t7 >> 8]));
      if      (T == 0) acc0 = __builtin_amdgcn_mfma_f32_16x16x32_f16(u.v, bc.h, acc0, 0,0,0);
      else if (T == 1) acc1 = __builtin_amdgcn_mfma_f32_16x16x32_f16(u.v, bc.h, acc1, 0,0,0);
      else if (T == 2) acc2 = __builtin_amdgcn_mfma_f32_16x16x32_f16(u.v, bc.h, acc2, 0,0,0);
      else             acc3 = __builtin_amdgcn_mfma_f32_16x16x32_f16(u.v, bc.h, acc3, 0,0,0);
    }
  };

  uint4 pf72 = make_uint4(0,0,0,0);
  if (tid < 64) pf72 = Bpan[72*64 + tid];
  for (int k = 0; k < 4; ++k)            // tiles 68..71 are in bsm[1] (staged by ss=16)
    tail_step(68 + k, bsm[1][k*64 + lane]);
  __syncthreads();
  if (tid < 64) bsm[0][tid] = pf72;
  __syncthreads();
  tail_step(72, bsm[0][lane]);

  // ---- epilogue ----
  int gp = lane >> 4, L = lane & 15;
#pragma unroll
  for (int T = 0; T < 4; ++T){
    f32x4 a = (T==0) ? acc0 : (T==1) ? acc1 : (T==2) ? acc2 : acc3;
    int rb = b0 + wid*64 + T*16;
#pragma unroll
    for (int r = 0; r < 4; ++r){
      int row = rb + 4*gp + r;
      if (row < cnt){
        int n = bins[e*NATOMS + row];
        out[((size_t)n*16 + L)*CCH + c] = a[r];
      }
    }
  }
}

extern "C" void kernel_launch(void* const* d_in, const int* in_sizes, int n_in,
                              void* d_out, int out_size, void* d_ws, size_t ws_size,
                              hipStream_t stream){
  const float* x   = (const float*)d_in[0];
  const int* types = (const int*)d_in[1];
  const float* U3  = (const float*)d_in[2];
  const float* U2  = (const float*)d_in[3];
  const float* U1  = (const float*)d_in[4];
  const float* W3  = (const float*)d_in[5];
  const float* W2  = (const float*)d_in[6];
  const float* W1  = (const float*)d_in[7];
  float* out = (float*)d_out;

  char* ws = (char*)d_ws;
  int* counts  = (int*)ws;               // +0    (16 B)
  int* bins    = (int*)(ws + 1024);      // +1024 (32 KB) -> ends 33792

  const size_t usOff   = 33792;                               // 512-aligned
  const size_t usBytes = (size_t)KPAD * 16 * 24 * 4;          // 3,588,096
  const size_t bbOff   = usOff + usBytes;                     // 3,621,888 (512-aligned)

  hipMemsetAsync(counts, 0, NE * sizeof(int), stream);

  float* Us = (float*)(ws + usOff);
  unsigned int* Bbuf = (unsigned int*)(ws + bbOff);
  int usymBlocks = (KPAD*16*6 + 255)/256;
  binusym_kernel<<<8 + usymBlocks, 256, 0, stream>>>(types, counts, bins, U3, U2, U1, Us);
  fold_kernel<<<dim3(NSTEP, NE), 256, 0, stream>>>(Us, W3, W2, W1, Bbuf);
  main4_kernel<<<dim3(MAXBS*64), 256, 0, stream>>>(x, counts, bins, (const uint4*)Bbuf, out);
}

// Round 11
// 87.376 us; speedup vs baseline: 1.2936x; 1.1481x over previous
//
#include <hip/hip_runtime.h>
#include <hip/hip_fp16.h>

#define NATOMS 2048
#define CCH    64
#define NE     4

#define NP    136     // #{i<=j} pairs over 16
#define K3DIM 2176    // 136*16 inflated order-3 K
#define M2B   2176
#define M1B   2312
#define KTOT  2328
#define KPAD  2336
#define NSTEP 73      // KPAD/32
#define MAXBS 12      // max 256-atom slots: sum ceil(cnt_e/256) <= 11

typedef _Float16 f16x8 __attribute__((ext_vector_type(8)));
typedef float f32x4 __attribute__((ext_vector_type(4)));

__host__ __device__ constexpr int pair_i(int p){ int i=0, rem=p; while (rem >= 16-i){ rem -= 16-i; ++i; } return i; }
__host__ __device__ constexpr int pair_j(int p){ int i=0, rem=p; while (rem >= 16-i){ rem -= 16-i; ++i; } return i+rem; }

// packed order-3 pair table: step s uses pairs 2s (lanes<32) and 2s+1 (lanes>=32)
struct PTab { unsigned v[68]; };
__host__ __device__ constexpr PTab make_ptab(){
  PTab t{};
  for (int s = 0; s < 68; ++s){
    int p0 = 2*s, p1 = 2*s + 1;
    t.v[s] = (unsigned)(pair_i(p0) | (pair_j(p0)<<5) | (pair_i(p1)<<10) | (pair_j(p1)<<15));
  }
  return t;
}
__device__ __constant__ PTab ptab = make_ptab();

__device__ __forceinline__ void slot_decode(const int* counts, int g,
                                            int& e, int& b0, int& cnt, int& ns){
  int c0 = counts[0], c1 = counts[1], c2 = counts[2], c3 = counts[3];
  int n0 = (c0+255)>>8, n1 = (c1+255)>>8, n2 = (c2+255)>>8, n3 = (c3+255)>>8;
  ns = n0 + n1 + n2 + n3;
  if (g < n0){ e = 0; b0 = g*256; cnt = c0; }
  else if (g < n0+n1){ e = 1; b0 = (g-n0)*256; cnt = c1; }
  else if (g < n0+n1+n2){ e = 2; b0 = (g-n0-n1)*256; cnt = c2; }
  else { e = 3; b0 = (g-n0-n1-n2)*256; cnt = c3; }
}

// ---------------- bin + usym merged ----------------
__global__ __launch_bounds__(256) void binusym_kernel(
    const int* __restrict__ types, int* counts, int* bins,
    const float* __restrict__ U3, const float* __restrict__ U2,
    const float* __restrict__ U1, float* __restrict__ Us){
  int b = blockIdx.x;
  if (b < 8){
    int n = b * 256 + threadIdx.x;
    if (n < NATOMS){
      int t = types[n];
      int pos = atomicAdd(&counts[t], 1);
      bins[t * NATOMS + pos] = n;
    }
    return;
  }
  int gid = (b - 8) * 256 + threadIdx.x;
  if (gid >= KPAD * 16 * 6) return;
  int q = gid % 6;
  int t2 = gid / 6;
  int L = t2 & 15, m = t2 >> 4;
  int w0 = q * 4;

  float v[4] = {0.f, 0.f, 0.f, 0.f};
  if (m < M2B){
    int p = m >> 4, k = m & 15;
    int i = 0, rem = p; while (rem >= 16 - i){ rem -= 16 - i; ++i; }
    int j = i + rem;
    const float* r0 = &U3[((((size_t)L*16 + i)*16 + j)*16 + k)*23];
    if (i < j){
      const float* r1 = &U3[((((size_t)L*16 + j)*16 + i)*16 + k)*23];
#pragma unroll
      for (int t = 0; t < 4; ++t){ int w = w0 + t; if (w < 23) v[t] = r0[w] + r1[w]; }
    } else {
#pragma unroll
      for (int t = 0; t < 4; ++t){ int w = w0 + t; if (w < 23) v[t] = r0[w]; }
    }
  } else if (m < M1B){
    if (w0 < 5){
      int p = m - M2B;
      int i = 0, rem = p; while (rem >= 16 - i){ rem -= 16 - i; ++i; }
      int j = i + rem;
#pragma unroll
      for (int t = 0; t < 4; ++t){
        int w = w0 + t;
        if (w < 5){
          float s = U2[(((size_t)L*16 + i)*16 + j)*5 + w];
          if (i < j) s += U2[(((size_t)L*16 + j)*16 + i)*5 + w];
          v[t] = s;
        }
      }
    }
  } else if (m < KTOT){
    if (w0 == 0){
      int i = m - M1B;
      v[0] = U1[((size_t)L*16 + i)*2 + 0];
      v[1] = U1[((size_t)L*16 + i)*2 + 1];
    }
  }
  float4* dst = (float4*)(Us + ((size_t)m*16 + L)*24 + w0);
  *dst = make_float4(v[0], v[1], v[2], v[3]);
}

// ---------------- xpose: x[n][i][c] f32 -> xT[c][slot][a][i] f16 (coalesced) ----------------
// block = 16 atoms of one slot; read 4KB/atom contiguous; LDS transpose; write f16.
__global__ __launch_bounds__(256) void xpose_kernel(
    const float* __restrict__ x, const int* __restrict__ counts,
    const int* __restrict__ bins, unsigned* __restrict__ xTu){
  int b = blockIdx.x;
  int g = b >> 4, asub = b & 15;
  int e, b0, cnt, ns;
  slot_decode(counts, g, e, b0, cnt, ns);
  if (g >= ns) return;

  __shared__ __half ls[16][1040];   // [a][c*16 + i], padded row
  int tid = threadIdx.x;
  int a_loc = tid >> 4, i = tid & 15;   // thread = (atom, i-plane)
  int row = b0 + asub*16 + a_loc;
  int n = (row < cnt) ? bins[e*NATOMS + row] : -1;

  if (n >= 0){
    const float4* src = (const float4*)(x + (size_t)n*1024 + (size_t)i*64);
#pragma unroll
    for (int q = 0; q < 16; ++q){
      float4 v = src[q];
      int c = q*4;
      ls[a_loc][(c+0)*16 + i] = __float2half(v.x);
      ls[a_loc][(c+1)*16 + i] = __float2half(v.y);
      ls[a_loc][(c+2)*16 + i] = __float2half(v.z);
      ls[a_loc][(c+3)*16 + i] = __float2half(v.w);
    }
  } else {
    __half z = __float2half(0.f);
#pragma unroll
    for (int q = 0; q < 16; ++q){
      int c = q*4;
      ls[a_loc][(c+0)*16 + i] = z;
      ls[a_loc][(c+1)*16 + i] = z;
      ls[a_loc][(c+2)*16 + i] = z;
      ls[a_loc][(c+3)*16 + i] = z;
    }
  }
  __syncthreads();

  int wid = tid >> 6, lane = tid & 63;
  for (int cp = 0; cp < 16; ++cp){
    int c = cp*4 + wid;
#pragma unroll
    for (int h = 0; h < 2; ++h){
      int a = h*8 + (lane >> 3), i2 = lane & 7;
      __half lo = ls[a][c*16 + 2*i2];
      __half hi = ls[a][c*16 + 2*i2 + 1];
      union { __half2 h2; unsigned u; } pk;
      pk.h2 = __halves2half2(lo, hi);
      xTu[((size_t)(c*MAXBS + g)*256 + asub*16 + a)*8 + i2] = pk.u;
    }
  }
}

// ---------------- fold: block per (s,e), all 64 channels ----------------
__global__ __launch_bounds__(256) void fold_kernel(
    const float* __restrict__ Us, const float* __restrict__ W3,
    const float* __restrict__ W2, const float* __restrict__ W1,
    unsigned int* __restrict__ Bbuf){
  int s = blockIdx.x, e = blockIdx.y;
  int tid = threadIdx.x;
  int l = tid >> 2, r = tid & 3, g = l >> 4, L = l & 15;
  int m0 = 32*s + 8*g + 2*r;

  __shared__ float WL[33][CCH];
  for (int t = tid; t < 33*CCH; t += 256){
    int row = t >> 6, cc = t & 63;
    float v = 0.f;
    if (row < 23)      v = W3[((size_t)e*23 + row)*CCH + cc];
    else if (row < 28) v = W2[((size_t)e*5 + (row-23))*CCH + cc];
    else if (row < 30) v = W1[((size_t)e*2 + (row-28))*CCH + cc];
    WL[row][cc] = v;
  }
  __syncthreads();

  const float4* s0 = (const float4*)(Us + ((size_t)m0*16 + L)*24);
  const float4* s1 = (const float4*)(Us + ((size_t)(m0+1)*16 + L)*24);

  const size_t ostride = (size_t)NSTEP*64*4;
  size_t obase = (((size_t)(e*CCH)*NSTEP + s)*64 + l)*4 + r;

  if (s < 68){
    float u0[24], u1[24];
#pragma unroll
    for (int q = 0; q < 6; ++q){ ((float4*)u0)[q] = s0[q]; ((float4*)u1)[q] = s1[q]; }
    for (int cc0 = 0; cc0 < CCH; cc0 += 4){
      float a0[4] = {0,0,0,0}, a1[4] = {0,0,0,0};
#pragma unroll
      for (int w = 0; w < 23; ++w){
#pragma unroll
        for (int q = 0; q < 4; ++q){
          float wv = WL[w][cc0+q];
          a0[q] += u0[w]*wv; a1[q] += u1[w]*wv;
        }
      }
#pragma unroll
      for (int q = 0; q < 4; ++q){
        union { __half2 h; unsigned int u; } hu;
        hu.h = __halves2half2(__float2half(a0[q]), __float2half(a1[q]));
        Bbuf[obase + (size_t)(cc0+q)*ostride] = hu.u;
      }
    }
  } else {
    float u0[8], u1[8];
    ((float4*)u0)[0] = s0[0]; ((float4*)u0)[1] = s0[1];
    ((float4*)u1)[0] = s1[0]; ((float4*)u1)[1] = s1[1];
    int wbase = (m0 < M1B) ? 23 : 28;
    for (int cc0 = 0; cc0 < CCH; cc0 += 4){
      float a0[4] = {0,0,0,0}, a1[4] = {0,0,0,0};
#pragma unroll
      for (int w = 0; w < 5; ++w){
#pragma unroll
        for (int q = 0; q < 4; ++q){
          float wv = WL[wbase + w][cc0+q];
          a0[q] += u0[w]*wv; a1[q] += u1[w]*wv;
        }
      }
#pragma unroll
      for (int q = 0; q < 4; ++q){
        union { __half2 h; unsigned int u; } hu;
        hu.h = __halves2half2(__float2half(a0[q]), __float2half(a1[q]));
        Bbuf[obase + (size_t)(cc0+q)*ostride] = hu.u;
      }
    }
  }
}

// ---------------- main5: runtime-looped MFMA GEMM, xT coalesced f16 input ----------------
__global__ __launch_bounds__(256, 3) void main5_kernel(
    const unsigned* __restrict__ xTu, const int* __restrict__ counts,
    const int* __restrict__ bins, const uint4* __restrict__ Bbuf,
    float* __restrict__ out){
  int v = (blockIdx.x & 7) * 96 + (blockIdx.x >> 3);   // bijective for 768
  int c = v / MAXBS;
  int g = v % MAXBS;
  int e, b0, cnt, ns;
  slot_decode(counts, g, e, b0, cnt, ns);
  if (g >= ns) return;

  int tid = threadIdx.x;
  int wid = tid >> 6, lane = tid & 63;

  __shared__ __half xe[4][256][18];      // 36,864 B
  __shared__ uint4  bsm[2][256];         //  8,192 B
  __shared__ unsigned ltab[160];         //    640 B

  bool hi_half = (lane & 16) != 0;
  bool gsel    = (lane & 32) != 0;

  // ---- coalesced x load from xT + xsel/xe build (all static indexing) ----
  const uint4* xr = ((const uint4*)xTu) + (size_t)(c*MAXBS + g)*256*2;
  __half2 xsel[4][4];
#pragma unroll
  for (int T = 0; T < 4; ++T){
    int arow = wid*64 + T*16 + (lane & 15);
    uint4 v0 = xr[arow*2 + 0];           // halfs 0..7  (i = 0..7)
    uint4 v1 = xr[arow*2 + 1];           // halfs 8..15
    union { unsigned u; __half2 h; } s0, s1, s2, s3;
    s0.u = hi_half ? v1.x : v0.x;
    s1.u = hi_half ? v1.y : v0.y;
    s2.u = hi_half ? v1.z : v0.z;
    s3.u = hi_half ? v1.w : v0.w;
    xsel[T][0] = s0.h; xsel[T][1] = s1.h; xsel[T][2] = s2.h; xsel[T][3] = s3.h;
    unsigned* xer = (unsigned*)&xe[T][tid][0];
    xer[0] = v0.x; xer[1] = v0.y; xer[2] = v0.z; xer[3] = v0.w;
    xer[4] = v1.x; xer[5] = v1.y; xer[6] = v1.z; xer[7] = v1.w;
    xer[8] = 0x00003C00u;                // halfs {1.0, 0.0} -> [16]=1, [17]=0
  }

  if (tid < 160){
    unsigned ij;
    if (tid < NP)        ij = (unsigned)(pair_i(tid) | (pair_j(tid) << 8));
    else if (tid < 152)  ij = (unsigned)((tid - NP) | (16 << 8));
    else                 ij = (unsigned)(17 | (17 << 8));
    ltab[tid] = ij;
  }

  const uint4* Bpan = Bbuf + (size_t)(e*CCH + c)*NSTEP*64;
  bsm[0][tid] = Bpan[tid];
  __syncthreads();

  f32x4 acc0 = {0,0,0,0}, acc1 = {0,0,0,0}, acc2 = {0,0,0,0}, acc3 = {0,0,0,0};

  for (int ss = 0; ss < 17; ++ss){
    uint4 pf = Bpan[(ss+1)*256 + tid];
    int cb = ss & 1;
    for (int k = 0; k < 4; ++k){
      uint4 cur = bsm[cb][k*64 + lane];
      unsigned pk = ptab.v[ss*4 + k];
      int iA = pk & 31, jA = (pk>>5) & 31, iB = (pk>>10) & 31, jB = (pk>>15) & 31;
      int isel = gsel ? iB : iA;
      int jsel = gsel ? jB : jA;
      union { uint4 u; f16x8 h; } bc; bc.u = cur;
#pragma unroll
      for (int T = 0; T < 4; ++T){
        __half p = __hmul(xe[T][tid][isel], xe[T][tid][jsel]);
        __half2 pv = __half2half2(p);
        union { __half2 h[4]; f16x8 v; } u;
#pragma unroll
        for (int q = 0; q < 4; ++q) u.h[q] = __hmul2(pv, xsel[T][q]);
        if      (T == 0) acc0 = __builtin_amdgcn_mfma_f32_16x16x32_f16(u.v, bc.h, acc0, 0,0,0);
        else if (T == 1) acc1 = __builtin_amdgcn_mfma_f32_16x16x32_f16(u.v, bc.h, acc1, 0,0,0);
        else if (T == 2) acc2 = __builtin_amdgcn_mfma_f32_16x16x32_f16(u.v, bc.h, acc2, 0,0,0);
        else             acc3 = __builtin_amdgcn_mfma_f32_16x16x32_f16(u.v, bc.h, acc3, 0,0,0);
      }
    }
    __syncthreads();
    bsm[cb ^ 1][tid] = pf;
    __syncthreads();
  }

  int g2 = (lane >> 4) & 3;
  auto tail_step = [&](int s, uint4 cur){
    int mb = 32*s + 8*g2 - M2B;
    unsigned t0 = ltab[mb+0], t1 = ltab[mb+1], t2 = ltab[mb+2], t3 = ltab[mb+3];
    unsigned t4 = ltab[mb+4], t5 = ltab[mb+5], t6 = ltab[mb+6], t7 = ltab[mb+7];
    union { uint4 u; f16x8 h; } bc; bc.u = cur;
#pragma unroll
    for (int T = 0; T < 4; ++T){
      union { __half2 h[4]; f16x8 v; } u;
      u.h[0] = __halves2half2(__hmul(xe[T][tid][t0 & 255], xe[T][tid][t0 >> 8]),
                              __hmul(xe[T][tid][t1 & 255], xe[T][tid][t1 >> 8]));
      u.h[1] = __halves2half2(__hmul(xe[T][tid][t2 & 255], xe[T][tid][t2 >> 8]),
                              __hmul(xe[T][tid][t3 & 255], xe[T][tid][t3 >> 8]));
      u.h[2] = __halves2half2(__hmul(xe[T][tid][t4 & 255], xe[T][tid][t4 >> 8]),
                              __hmul(xe[T][tid][t5 & 255], xe[T][tid][t5 >> 8]));
      u.h[3] = __halves2half2(__hmul(xe[T][tid][t6 & 255], xe[T][tid][t6 >> 8]),
                              __hmul(xe[T][tid][t7 & 255], xe[T][tid][t7 >> 8]));
      if      (T == 0) acc0 = __builtin_amdgcn_mfma_f32_16x16x32_f16(u.v, bc.h, acc0, 0,0,0);
      else if (T == 1) acc1 = __builtin_amdgcn_mfma_f32_16x16x32_f16(u.v, bc.h, acc1, 0,0,0);
      else if (T == 2) acc2 = __builtin_amdgcn_mfma_f32_16x16x32_f16(u.v, bc.h, acc2, 0,0,0);
      else             acc3 = __builtin_amdgcn_mfma_f32_16x16x32_f16(u.v, bc.h, acc3, 0,0,0);
    }
  };

  uint4 pf72 = make_uint4(0,0,0,0);
  if (tid < 64) pf72 = Bpan[72*64 + tid];
  for (int k = 0; k < 4; ++k)
    tail_step(68 + k, bsm[1][k*64 + lane]);
  __syncthreads();
  if (tid < 64) bsm[0][tid] = pf72;
  __syncthreads();
  tail_step(72, bsm[0][lane]);

  int gp = lane >> 4, L = lane & 15;
#pragma unroll
  for (int T = 0; T < 4; ++T){
    f32x4 a = (T==0) ? acc0 : (T==1) ? acc1 : (T==2) ? acc2 : acc3;
    int rb = b0 + wid*64 + T*16;
#pragma unroll
    for (int r = 0; r < 4; ++r){
      int row = rb + 4*gp + r;
      if (row < cnt){
        int n = bins[e*NATOMS + row];
        out[((size_t)n*16 + L)*CCH + c] = a[r];
      }
    }
  }
}

// ---------------- main4: fallback (direct gather) for small ws ----------------
__global__ __launch_bounds__(256, 3) void main4_kernel(
    const float* __restrict__ x, const int* __restrict__ counts,
    const int* __restrict__ bins, const uint4* __restrict__ Bbuf,
    float* __restrict__ out){
  int v = (blockIdx.x & 7) * 96 + (blockIdx.x >> 3);
  int c = v / MAXBS;
  int g = v % MAXBS;
  int e, b0, cnt, ns;
  slot_decode(counts, g, e, b0, cnt, ns);
  if (g >= ns) return;

  int tid = threadIdx.x;
  int wid = tid >> 6, lane = tid & 63;

  __shared__ __half xe[4][256][18];
  __shared__ uint4  bsm[2][256];
  __shared__ unsigned ltab[160];

  float xa[4][16];
#pragma unroll
  for (int T = 0; T < 4; ++T){
    int row = b0 + wid*64 + T*16 + (lane & 15);
    int n = (row < cnt) ? bins[e*NATOMS + row] : -1;
#pragma unroll
    for (int i = 0; i < 16; ++i)
      xa[T][i] = (n >= 0) ? x[((size_t)n*16 + i)*CCH + c] : 0.f;
  }

  bool hi_half = (lane & 16) != 0;
  bool gsel    = (lane & 32) != 0;
  __half2 xsel[4][4];
#pragma unroll
  for (int T = 0; T < 4; ++T){
#pragma unroll
    for (int q = 0; q < 4; ++q){
      __half2 lo = __halves2half2(__float2half(xa[T][2*q]),   __float2half(xa[T][2*q+1]));
      __half2 hi = __halves2half2(__float2half(xa[T][8+2*q]), __float2half(xa[T][8+2*q+1]));
      xsel[T][q] = hi_half ? hi : lo;
    }
  }
#pragma unroll
  for (int T = 0; T < 4; ++T){
#pragma unroll
    for (int i = 0; i < 16; ++i) xe[T][tid][i] = __float2half(xa[T][i]);
    xe[T][tid][16] = __float2half(1.0f);
    xe[T][tid][17] = __float2half(0.0f);
  }

  if (tid < 160){
    unsigned ij;
    if (tid < NP)        ij = (unsigned)(pair_i(tid) | (pair_j(tid) << 8));
    else if (tid < 152)  ij = (unsigned)((tid - NP) | (16 << 8));
    else                 ij = (unsigned)(17 | (17 << 8));
    ltab[tid] = ij;
  }

  const uint4* Bpan = Bbuf + (size_t)(e*CCH + c)*NSTEP*64;
  bsm[0][tid] = Bpan[tid];
  __syncthreads();

  f32x4 acc0 = {0,0,0,0}, acc1 = {0,0,0,0}, acc2 = {0,0,0,0}, acc3 = {0,0,0,0};

  for (int ss = 0; ss < 17; ++ss){
    uint4 pf = Bpan[(ss+1)*256 + tid];
    int cb = ss & 1;
    for (int k = 0; k < 4; ++k){
      uint4 cur = bsm[cb][k*64 + lane];
      unsigned pk = ptab.v[ss*4 + k];
      int iA = pk & 31, jA = (pk>>5) & 31, iB = (pk>>10) & 31, jB = (pk>>15) & 31;
      int isel = gsel ? iB : iA;
      int jsel = gsel ? jB : jA;
      union { uint4 u; f16x8 h; } bc; bc.u = cur;
#pragma unroll
      for (int T = 0; T < 4; ++T){
        __half p = __hmul(xe[T][tid][isel], xe[T][tid][jsel]);
        __half2 pv = __half2half2(p);
        union { __half2 h[4]; f16x8 v; } u;
#pragma unroll
        for (int q = 0; q < 4; ++q) u.h[q] = __hmul2(pv, xsel[T][q]);
        if      (T == 0) acc0 = __builtin_amdgcn_mfma_f32_16x16x32_f16(u.v, bc.h, acc0, 0,0,0);
        else if (T == 1) acc1 = __builtin_amdgcn_mfma_f32_16x16x32_f16(u.v, bc.h, acc1, 0,0,0);
        else if (T == 2) acc2 = __builtin_amdgcn_mfma_f32_16x16x32_f16(u.v, bc.h, acc2, 0,0,0);
        else             acc3 = __builtin_amdgcn_mfma_f32_16x16x32_f16(u.v, bc.h, acc3, 0,0,0);
      }
    }
    __syncthreads();
    bsm[cb ^ 1][tid] = pf;
    __syncthreads();
  }

  int g2 = (lane >> 4) & 3;
  auto tail_step = [&](int s, uint4 cur){
    int mb = 32*s + 8*g2 - M2B;
    unsigned t0 = ltab[mb+0], t1 = ltab[mb+1], t2 = ltab[mb+2], t3 = ltab[mb+3];
    unsigned t4 = ltab[mb+4], t5 = ltab[mb+5], t6 = ltab[mb+6], t7 = ltab[mb+7];
    union { uint4 u; f16x8 h; } bc; bc.u = cur;
#pragma unroll
    for (int T = 0; T < 4; ++T){
      union { __half2 h[4]; f16x8 v; } u;
      u.h[0] = __halves2half2(__hmul(xe[T][tid][t0 & 255], xe[T][tid][t0 >> 8]),
                              __hmul(xe[T][tid][t1 & 255], xe[T][tid][t1 >> 8]));
      u.h[1] = __halves2half2(__hmul(xe[T][tid][t2 & 255], xe[T][tid][t2 >> 8]),
                              __hmul(xe[T][tid][t3 & 255], xe[T][tid][t3 >> 8]));
      u.h[2] = __halves2half2(__hmul(xe[T][tid][t4 & 255], xe[T][tid][t4 >> 8]),
                              __hmul(xe[T][tid][t5 & 255], xe[T][tid][t5 >> 8]));
      u.h[3] = __halves2half2(__hmul(xe[T][tid][t6 & 255], xe[T][tid][t6 >> 8]),
                              __hmul(xe[T][tid][t7 & 255], xe[T][tid][t7 >> 8]));
      if      (T == 0) acc0 = __builtin_amdgcn_mfma_f32_16x16x32_f16(u.v, bc.h, acc0, 0,0,0);
      else if (T == 1) acc1 = __builtin_amdgcn_mfma_f32_16x16x32_f16(u.v, bc.h, acc1, 0,0,0);
      else if (T == 2) acc2 = __builtin_amdgcn_mfma_f32_16x16x32_f16(u.v, bc.h, acc2, 0,0,0);
      else             acc3 = __builtin_amdgcn_mfma_f32_16x16x32_f16(u.v, bc.h, acc3, 0,0,0);
    }
  };

  uint4 pf72 = make_uint4(0,0,0,0);
  if (tid < 64) pf72 = Bpan[72*64 + tid];
  for (int k = 0; k < 4; ++k)
    tail_step(68 + k, bsm[1][k*64 + lane]);
  __syncthreads();
  if (tid < 64) bsm[0][tid] = pf72;
  __syncthreads();
  tail_step(72, bsm[0][lane]);

  int gp = lane >> 4, L = lane & 15;
#pragma unroll
  for (int T = 0; T < 4; ++T){
    f32x4 a = (T==0) ? acc0 : (T==1) ? acc1 : (T==2) ? acc2 : acc3;
    int rb = b0 + wid*64 + T*16;
#pragma unroll
    for (int r = 0; r < 4; ++r){
      int row = rb + 4*gp + r;
      if (row < cnt){
        int n = bins[e*NATOMS + row];
        out[((size_t)n*16 + L)*CCH + c] = a[r];
      }
    }
  }
}

extern "C" void kernel_launch(void* const* d_in, const int* in_sizes, int n_in,
                              void* d_out, int out_size, void* d_ws, size_t ws_size,
                              hipStream_t stream){
  const float* x   = (const float*)d_in[0];
  const int* types = (const int*)d_in[1];
  const float* U3  = (const float*)d_in[2];
  const float* U2  = (const float*)d_in[3];
  const float* U1  = (const float*)d_in[4];
  const float* W3  = (const float*)d_in[5];
  const float* W2  = (const float*)d_in[6];
  const float* W1  = (const float*)d_in[7];
  float* out = (float*)d_out;

  char* ws = (char*)d_ws;
  int* counts  = (int*)ws;               // +0    (16 B)
  int* bins    = (int*)(ws + 1024);      // +1024 (32 KB) -> ends 33792

  const size_t usOff   = 33792;
  const size_t usBytes = (size_t)KPAD * 16 * 24 * 4;          // 3,588,096
  const size_t bbOff   = usOff + usBytes;                     // 3,621,888
  const size_t bbBytes = (size_t)NE * 64 * NSTEP * 64 * 16;   // 19,136,512
  const size_t xtOff   = bbOff + bbBytes;                     // 22,758,400 (512-aligned)
  const size_t xtBytes = (size_t)CCH * MAXBS * 256 * 16 * 2;  // 9,437,184

  hipMemsetAsync(counts, 0, NE * sizeof(int), stream);

  float* Us = (float*)(ws + usOff);
  unsigned int* Bbuf = (unsigned int*)(ws + bbOff);
  int usymBlocks = (KPAD*16*6 + 255)/256;
  binusym_kernel<<<8 + usymBlocks, 256, 0, stream>>>(types, counts, bins, U3, U2, U1, Us);

  if (ws_size >= xtOff + xtBytes){
    unsigned* xTu = (unsigned*)(ws + xtOff);
    xpose_kernel<<<MAXBS*16, 256, 0, stream>>>(x, counts, bins, xTu);
    fold_kernel<<<dim3(NSTEP, NE), 256, 0, stream>>>(Us, W3, W2, W1, Bbuf);
    main5_kernel<<<dim3(MAXBS*64), 256, 0, stream>>>(xTu, counts, bins, (const uint4*)Bbuf, out);
  } else {
    fold_kernel<<<dim3(NSTEP, NE), 256, 0, stream>>>(Us, W3, W2, W1, Bbuf);
    main4_kernel<<<dim3(MAXBS*64), 256, 0, stream>>>(x, counts, bins, (const uint4*)Bbuf, out);
  }
}

// Round 12
// 78.453 us; speedup vs baseline: 1.4407x; 1.1137x over previous
//
#include <hip/hip_runtime.h>
#include <hip/hip_fp16.h>

#define NATOMS 2048
#define CCH    64
#define NE     4

#define NP    136     // #{i<=j} pairs over 16
#define K3DIM 2176
#define M2B   2176
#define M1B   2312
#define KTOT  2328
#define KPAD  2336
#define NSTEP 73      // KPAD/32
#define MAXBS 12      // max 256-atom slots

typedef _Float16 f16x8 __attribute__((ext_vector_type(8)));
typedef float f32x4 __attribute__((ext_vector_type(4)));

__host__ __device__ constexpr int pair_i(int p){ int i=0, rem=p; while (rem >= 16-i){ rem -= 16-i; ++i; } return i; }
__host__ __device__ constexpr int pair_j(int p){ int i=0, rem=p; while (rem >= 16-i){ rem -= 16-i; ++i; } return i+rem; }

struct PTab { unsigned v[68]; };
__host__ __device__ constexpr PTab make_ptab(){
  PTab t{};
  for (int s = 0; s < 68; ++s){
    int p0 = 2*s, p1 = 2*s + 1;
    t.v[s] = (unsigned)(pair_i(p0) | (pair_j(p0)<<5) | (pair_i(p1)<<10) | (pair_j(p1)<<15));
  }
  return t;
}
__device__ __constant__ PTab ptab = make_ptab();

__device__ __forceinline__ void slot_decode(const int* counts, int g,
                                            int& e, int& b0, int& cnt, int& ns){
  int c0 = counts[0], c1 = counts[1], c2 = counts[2], c3 = counts[3];
  int n0 = (c0+255)>>8, n1 = (c1+255)>>8, n2 = (c2+255)>>8, n3 = (c3+255)>>8;
  ns = n0 + n1 + n2 + n3;
  if (g < n0){ e = 0; b0 = g*256; cnt = c0; }
  else if (g < n0+n1){ e = 1; b0 = (g-n0)*256; cnt = c1; }
  else if (g < n0+n1+n2){ e = 2; b0 = (g-n0-n1)*256; cnt = c2; }
  else { e = 3; b0 = (g-n0-n1-n2)*256; cnt = c3; }
}

// pack: a={a0,a1} halfs, b={b0,b1} -> lo={a0,b0}, hi={a1,b1}
__device__ __forceinline__ void pack2(unsigned a, unsigned b, unsigned& lo, unsigned& hi){
  lo = (a & 0xFFFFu) | (b << 16);
  hi = (a >> 16) | (b & 0xFFFF0000u);
}

// ---------------- bin + usym merged ----------------
__global__ __launch_bounds__(256) void binusym_kernel(
    const int* __restrict__ types, int* counts, int* bins,
    const float* __restrict__ U3, const float* __restrict__ U2,
    const float* __restrict__ U1, float* __restrict__ Us){
  int b = blockIdx.x;
  if (b < 8){
    int n = b * 256 + threadIdx.x;
    if (n < NATOMS){
      int t = types[n];
      int pos = atomicAdd(&counts[t], 1);
      bins[t * NATOMS + pos] = n;
    }
    return;
  }
  int gid = (b - 8) * 256 + threadIdx.x;
  if (gid >= KPAD * 16 * 6) return;
  int q = gid % 6;
  int t2 = gid / 6;
  int L = t2 & 15, m = t2 >> 4;
  int w0 = q * 4;

  float v[4] = {0.f, 0.f, 0.f, 0.f};
  if (m < M2B){
    int p = m >> 4, k = m & 15;
    int i = 0, rem = p; while (rem >= 16 - i){ rem -= 16 - i; ++i; }
    int j = i + rem;
    const float* r0 = &U3[((((size_t)L*16 + i)*16 + j)*16 + k)*23];
    if (i < j){
      const float* r1 = &U3[((((size_t)L*16 + j)*16 + i)*16 + k)*23];
#pragma unroll
      for (int t = 0; t < 4; ++t){ int w = w0 + t; if (w < 23) v[t] = r0[w] + r1[w]; }
    } else {
#pragma unroll
      for (int t = 0; t < 4; ++t){ int w = w0 + t; if (w < 23) v[t] = r0[w]; }
    }
  } else if (m < M1B){
    if (w0 < 5){
      int p = m - M2B;
      int i = 0, rem = p; while (rem >= 16 - i){ rem -= 16 - i; ++i; }
      int j = i + rem;
#pragma unroll
      for (int t = 0; t < 4; ++t){
        int w = w0 + t;
        if (w < 5){
          float s = U2[(((size_t)L*16 + i)*16 + j)*5 + w];
          if (i < j) s += U2[(((size_t)L*16 + j)*16 + i)*5 + w];
          v[t] = s;
        }
      }
    }
  } else if (m < KTOT){
    if (w0 == 0){
      int i = m - M1B;
      v[0] = U1[((size_t)L*16 + i)*2 + 0];
      v[1] = U1[((size_t)L*16 + i)*2 + 1];
    }
  }
  float4* dst = (float4*)(Us + ((size_t)m*16 + L)*24 + w0);
  *dst = make_float4(v[0], v[1], v[2], v[3]);
}

// ---------------- prep2: fold (blocks 0..291) + xpose (blocks 292..483) ----------------
__global__ __launch_bounds__(256) void prep2_kernel(
    const float* __restrict__ Us, const float* __restrict__ W3,
    const float* __restrict__ W2, const float* __restrict__ W1,
    unsigned int* __restrict__ Bbuf,
    const float* __restrict__ x, const int* __restrict__ counts,
    const int* __restrict__ bins, unsigned* __restrict__ xTu){
  __shared__ char smem[33280];
  int blk = blockIdx.x;
  int tid = threadIdx.x;

  if (blk < NSTEP*NE){
    // ---------- fold ----------
    int s = blk % NSTEP, e = blk / NSTEP;
    int l = tid >> 2, r = tid & 3, g = l >> 4, L = l & 15;
    int m0 = 32*s + 8*g + 2*r;
    float (*WL)[CCH] = (float(*)[CCH])smem;   // [33][64]

    for (int t = tid; t < 33*CCH; t += 256){
      int row = t >> 6, cc = t & 63;
      float v = 0.f;
      if (row < 23)      v = W3[((size_t)e*23 + row)*CCH + cc];
      else if (row < 28) v = W2[((size_t)e*5 + (row-23))*CCH + cc];
      else if (row < 30) v = W1[((size_t)e*2 + (row-28))*CCH + cc];
      WL[row][cc] = v;
    }
    __syncthreads();

    const float4* s0 = (const float4*)(Us + ((size_t)m0*16 + L)*24);
    const float4* s1 = (const float4*)(Us + ((size_t)(m0+1)*16 + L)*24);
    const size_t ostride = (size_t)NSTEP*64*4;
    size_t obase = (((size_t)(e*CCH)*NSTEP + s)*64 + l)*4 + r;

    if (s < 68){
      float u0[24], u1[24];
#pragma unroll
      for (int q = 0; q < 6; ++q){ ((float4*)u0)[q] = s0[q]; ((float4*)u1)[q] = s1[q]; }
      for (int cc0 = 0; cc0 < CCH; cc0 += 4){
        float a0[4] = {0,0,0,0}, a1[4] = {0,0,0,0};
#pragma unroll
        for (int w = 0; w < 23; ++w){
#pragma unroll
          for (int q = 0; q < 4; ++q){
            float wv = WL[w][cc0+q];
            a0[q] += u0[w]*wv; a1[q] += u1[w]*wv;
          }
        }
#pragma unroll
        for (int q = 0; q < 4; ++q){
          union { __half2 h; unsigned int u; } hu;
          hu.h = __halves2half2(__float2half(a0[q]), __float2half(a1[q]));
          Bbuf[obase + (size_t)(cc0+q)*ostride] = hu.u;
        }
      }
    } else {
      float u0[8], u1[8];
      ((float4*)u0)[0] = s0[0]; ((float4*)u0)[1] = s0[1];
      ((float4*)u1)[0] = s1[0]; ((float4*)u1)[1] = s1[1];
      int wbase = (m0 < M1B) ? 23 : 28;
      for (int cc0 = 0; cc0 < CCH; cc0 += 4){
        float a0[4] = {0,0,0,0}, a1[4] = {0,0,0,0};
#pragma unroll
        for (int w = 0; w < 5; ++w){
#pragma unroll
          for (int q = 0; q < 4; ++q){
            float wv = WL[wbase + w][cc0+q];
            a0[q] += u0[w]*wv; a1[q] += u1[w]*wv;
          }
        }
#pragma unroll
        for (int q = 0; q < 4; ++q){
          union { __half2 h; unsigned int u; } hu;
          hu.h = __halves2half2(__float2half(a0[q]), __float2half(a1[q]));
          Bbuf[obase + (size_t)(cc0+q)*ostride] = hu.u;
        }
      }
    }
    return;
  }

  // ---------- xpose ----------
  int b2 = blk - NSTEP*NE;
  int g = b2 >> 4, asub = b2 & 15;
  int e, b0, cnt, ns;
  slot_decode(counts, g, e, b0, cnt, ns);
  if (g >= ns) return;

  __half (*ls)[1040] = (__half(*)[1040])smem;   // [16][1040]
  int a_loc = tid >> 4, i = tid & 15;
  int row = b0 + asub*16 + a_loc;
  int n = (row < cnt) ? bins[e*NATOMS + row] : -1;

  if (n >= 0){
    const float4* src = (const float4*)(x + (size_t)n*1024 + (size_t)i*64);
#pragma unroll
    for (int q = 0; q < 16; ++q){
      float4 v = src[q];
      int c = q*4;
      ls[a_loc][(c+0)*16 + i] = __float2half(v.x);
      ls[a_loc][(c+1)*16 + i] = __float2half(v.y);
      ls[a_loc][(c+2)*16 + i] = __float2half(v.z);
      ls[a_loc][(c+3)*16 + i] = __float2half(v.w);
    }
  } else {
    __half z = __float2half(0.f);
#pragma unroll
    for (int q = 0; q < 16; ++q){
      int c = q*4;
      ls[a_loc][(c+0)*16 + i] = z;
      ls[a_loc][(c+1)*16 + i] = z;
      ls[a_loc][(c+2)*16 + i] = z;
      ls[a_loc][(c+3)*16 + i] = z;
    }
  }
  __syncthreads();

  int wid = tid >> 6, lane = tid & 63;
  for (int cp = 0; cp < 16; ++cp){
    int c = cp*4 + wid;
#pragma unroll
    for (int h = 0; h < 2; ++h){
      int a = h*8 + (lane >> 3), i2 = lane & 7;
      __half lo = ls[a][c*16 + 2*i2];
      __half hi = ls[a][c*16 + 2*i2 + 1];
      union { __half2 h2; unsigned u; } pk;
      pk.h2 = __halves2half2(lo, hi);
      xTu[((size_t)(c*MAXBS + g)*256 + asub*16 + a)*8 + i2] = pk.u;
    }
  }
}

// ---------------- main6: barrier-free runtime loop, T-packed LDS, direct-B ----------------
__global__ __launch_bounds__(256, 4) void main6_kernel(
    const unsigned* __restrict__ xTu, const int* __restrict__ counts,
    const int* __restrict__ bins, const uint4* __restrict__ Bbuf,
    float* __restrict__ out){
  int v = (blockIdx.x & 7) * 96 + (blockIdx.x >> 3);   // bijective for 768
  int c = v / MAXBS;
  int g = v % MAXBS;
  int e, b0, cnt, ns;
  slot_decode(counts, g, e, b0, cnt, ns);
  if (g >= ns) return;

  int tid = threadIdx.x;
  int wid = tid >> 6, lane = tid & 63;

  __shared__ unsigned xe01[256][19];     // {T0,T1} half2 per entry; 19,456 B
  __shared__ unsigned xe23[256][19];     // {T2,T3}                ; 19,456 B
  __shared__ unsigned ltab[160];         //    640 B

  bool hi_half = (lane & 16) != 0;
  bool gsel    = (lane & 32) != 0;

  // ---- coalesced x load + xsel + packed xe build ----
  const uint4* xr = ((const uint4*)xTu) + (size_t)(c*MAXBS + g)*256*2;
  uint4 tv0[4], tv1[4];
  __half2 xsel[4][4];
#pragma unroll
  for (int T = 0; T < 4; ++T){
    int arow = wid*64 + T*16 + (lane & 15);
    tv0[T] = xr[arow*2 + 0];
    tv1[T] = xr[arow*2 + 1];
    union { unsigned u; __half2 h; } s0, s1, s2, s3;
    s0.u = hi_half ? tv1[T].x : tv0[T].x;
    s1.u = hi_half ? tv1[T].y : tv0[T].y;
    s2.u = hi_half ? tv1[T].z : tv0[T].z;
    s3.u = hi_half ? tv1[T].w : tv0[T].w;
    xsel[T][0] = s0.h; xsel[T][1] = s1.h; xsel[T][2] = s2.h; xsel[T][3] = s3.h;
  }
  {
    unsigned lo, hi;
    pack2(tv0[0].x, tv0[1].x, lo, hi); xe01[tid][0] = lo; xe01[tid][1] = hi;
    pack2(tv0[0].y, tv0[1].y, lo, hi); xe01[tid][2] = lo; xe01[tid][3] = hi;
    pack2(tv0[0].z, tv0[1].z, lo, hi); xe01[tid][4] = lo; xe01[tid][5] = hi;
    pack2(tv0[0].w, tv0[1].w, lo, hi); xe01[tid][6] = lo; xe01[tid][7] = hi;
    pack2(tv1[0].x, tv1[1].x, lo, hi); xe01[tid][8] = lo; xe01[tid][9] = hi;
    pack2(tv1[0].y, tv1[1].y, lo, hi); xe01[tid][10] = lo; xe01[tid][11] = hi;
    pack2(tv1[0].z, tv1[1].z, lo, hi); xe01[tid][12] = lo; xe01[tid][13] = hi;
    pack2(tv1[0].w, tv1[1].w, lo, hi); xe01[tid][14] = lo; xe01[tid][15] = hi;
    xe01[tid][16] = 0x3C003C00u; xe01[tid][17] = 0u;
    pack2(tv0[2].x, tv0[3].x, lo, hi); xe23[tid][0] = lo; xe23[tid][1] = hi;
    pack2(tv0[2].y, tv0[3].y, lo, hi); xe23[tid][2] = lo; xe23[tid][3] = hi;
    pack2(tv0[2].z, tv0[3].z, lo, hi); xe23[tid][4] = lo; xe23[tid][5] = hi;
    pack2(tv0[2].w, tv0[3].w, lo, hi); xe23[tid][6] = lo; xe23[tid][7] = hi;
    pack2(tv1[2].x, tv1[3].x, lo, hi); xe23[tid][8] = lo; xe23[tid][9] = hi;
    pack2(tv1[2].y, tv1[3].y, lo, hi); xe23[tid][10] = lo; xe23[tid][11] = hi;
    pack2(tv1[2].z, tv1[3].z, lo, hi); xe23[tid][12] = lo; xe23[tid][13] = hi;
    pack2(tv1[2].w, tv1[3].w, lo, hi); xe23[tid][14] = lo; xe23[tid][15] = hi;
    xe23[tid][16] = 0x3C003C00u; xe23[tid][17] = 0u;
  }
  if (tid < 160){
    unsigned ij;
    if (tid < NP)        ij = (unsigned)(pair_i(tid) | (pair_j(tid) << 8));
    else if (tid < 152)  ij = (unsigned)((tid - NP) | (16 << 8));
    else                 ij = (unsigned)(17 | (17 << 8));
    ltab[tid] = ij;
  }
  __syncthreads();   // once: xe/ltab visible to own block (waves are independent after)

  const uint4* Bpan = Bbuf + (size_t)(e*CCH + c)*NSTEP*64 + lane;

  f32x4 acc0 = {0,0,0,0}, acc1 = {0,0,0,0}, acc2 = {0,0,0,0}, acc3 = {0,0,0,0};

  uint4 pb0 = Bpan[0*64], pb1 = Bpan[1*64], pb2 = Bpan[2*64], pb3 = Bpan[3*64];

#pragma unroll 4
  for (int s = 0; s < 68; ++s){
    uint4 cur = pb0; pb0 = pb1; pb1 = pb2; pb2 = pb3;
    int ld = (s + 4 <= 72) ? (s + 4) : 72;
    pb3 = Bpan[(size_t)ld*64];

    unsigned pk = ptab.v[s];
    int iA = pk & 31, jA = (pk>>5) & 31, iB = (pk>>10) & 31, jB = (pk>>15) & 31;
    int isel = gsel ? iB : iA;
    int jsel = gsel ? jB : jA;

    union { unsigned u; __half2 h; } pi01, pj01, pi23, pj23;
    pi01.u = xe01[tid][isel]; pj01.u = xe01[tid][jsel];
    pi23.u = xe23[tid][isel]; pj23.u = xe23[tid][jsel];
    __half2 p01 = __hmul2(pi01.h, pj01.h);   // {pT0, pT1}
    __half2 p23 = __hmul2(pi23.h, pj23.h);   // {pT2, pT3}

    union { uint4 u; f16x8 h; } bc; bc.u = cur;
    __half2 pv0 = __half2half2(__low2half(p01));
    __half2 pv1 = __half2half2(__high2half(p01));
    __half2 pv2 = __half2half2(__low2half(p23));
    __half2 pv3 = __half2half2(__high2half(p23));
    union { __half2 h[4]; f16x8 v; } u0, u1, u2, u3;
#pragma unroll
    for (int q = 0; q < 4; ++q){
      u0.h[q] = __hmul2(pv0, xsel[0][q]);
      u1.h[q] = __hmul2(pv1, xsel[1][q]);
      u2.h[q] = __hmul2(pv2, xsel[2][q]);
      u3.h[q] = __hmul2(pv3, xsel[3][q]);
    }
    acc0 = __builtin_amdgcn_mfma_f32_16x16x32_f16(u0.v, bc.h, acc0, 0,0,0);
    acc1 = __builtin_amdgcn_mfma_f32_16x16x32_f16(u1.v, bc.h, acc1, 0,0,0);
    acc2 = __builtin_amdgcn_mfma_f32_16x16x32_f16(u2.v, bc.h, acc2, 0,0,0);
    acc3 = __builtin_amdgcn_mfma_f32_16x16x32_f16(u3.v, bc.h, acc3, 0,0,0);
  }

  // ---- tail: steps 68..72 via element table ----
  int g2 = (lane >> 4) & 3;
#pragma unroll
  for (int s = 68; s < 73; ++s){
    uint4 cur = pb0; pb0 = pb1; pb1 = pb2; pb2 = pb3;
    pb3 = Bpan[(size_t)72*64];
    int mb = 32*s + 8*g2 - M2B;
    union { uint4 u; f16x8 h; } bc; bc.u = cur;
    union { __half2 h[4]; f16x8 v; } u0, u1, u2, u3;
#pragma unroll
    for (int q = 0; q < 4; ++q){
      unsigned ta = ltab[mb + 2*q], tb = ltab[mb + 2*q + 1];
      union { unsigned u; __half2 h; } a01, b01, a23, b23, c01, d01, c23, d23;
      a01.u = xe01[tid][ta & 255]; b01.u = xe01[tid][ta >> 8];
      c01.u = xe01[tid][tb & 255]; d01.u = xe01[tid][tb >> 8];
      a23.u = xe23[tid][ta & 255]; b23.u = xe23[tid][ta >> 8];
      c23.u = xe23[tid][tb & 255]; d23.u = xe23[tid][tb >> 8];
      __half2 pa01 = __hmul2(a01.h, b01.h);   // {p_a T0, p_a T1}
      __half2 pb01_ = __hmul2(c01.h, d01.h);  // {p_b T0, p_b T1}
      __half2 pa23 = __hmul2(a23.h, b23.h);
      __half2 pb23_ = __hmul2(c23.h, d23.h);
      u0.h[q] = __halves2half2(__low2half(pa01),  __low2half(pb01_));
      u1.h[q] = __halves2half2(__high2half(pa01), __high2half(pb01_));
      u2.h[q] = __halves2half2(__low2half(pa23),  __low2half(pb23_));
      u3.h[q] = __halves2half2(__high2half(pa23), __high2half(pb23_));
    }
    acc0 = __builtin_amdgcn_mfma_f32_16x16x32_f16(u0.v, bc.h, acc0, 0,0,0);
    acc1 = __builtin_amdgcn_mfma_f32_16x16x32_f16(u1.v, bc.h, acc1, 0,0,0);
    acc2 = __builtin_amdgcn_mfma_f32_16x16x32_f16(u2.v, bc.h, acc2, 0,0,0);
    acc3 = __builtin_amdgcn_mfma_f32_16x16x32_f16(u3.v, bc.h, acc3, 0,0,0);
  }

  // ---- epilogue ----
  int gp = lane >> 4, L = lane & 15;
#pragma unroll
  for (int T = 0; T < 4; ++T){
    f32x4 a = (T==0) ? acc0 : (T==1) ? acc1 : (T==2) ? acc2 : acc3;
    int rb = b0 + wid*64 + T*16;
#pragma unroll
    for (int r = 0; r < 4; ++r){
      int row = rb + 4*gp + r;
      if (row < cnt){
        int n = bins[e*NATOMS + row];
        out[((size_t)n*16 + L)*CCH + c] = a[r];
      }
    }
  }
}

extern "C" void kernel_launch(void* const* d_in, const int* in_sizes, int n_in,
                              void* d_out, int out_size, void* d_ws, size_t ws_size,
                              hipStream_t stream){
  const float* x   = (const float*)d_in[0];
  const int* types = (const int*)d_in[1];
  const float* U3  = (const float*)d_in[2];
  const float* U2  = (const float*)d_in[3];
  const float* U1  = (const float*)d_in[4];
  const float* W3  = (const float*)d_in[5];
  const float* W2  = (const float*)d_in[6];
  const float* W1  = (const float*)d_in[7];
  float* out = (float*)d_out;

  char* ws = (char*)d_ws;
  int* counts  = (int*)ws;               // +0    (16 B)
  int* bins    = (int*)(ws + 1024);      // +1024 (32 KB)

  const size_t usOff   = 33792;
  const size_t usBytes = (size_t)KPAD * 16 * 24 * 4;          // 3,588,096
  const size_t bbOff   = usOff + usBytes;                     // 3,621,888
  const size_t bbBytes = (size_t)NE * 64 * NSTEP * 64 * 16;   // 19,136,512
  const size_t xtOff   = bbOff + bbBytes;                     // 22,758,400
  // xtBytes = 9,437,184 ; total ~32.2 MB (proven to fit in rounds 9-11)

  hipMemsetAsync(counts, 0, NE * sizeof(int), stream);

  float* Us = (float*)(ws + usOff);
  unsigned int* Bbuf = (unsigned int*)(ws + bbOff);
  unsigned* xTu = (unsigned*)(ws + xtOff);

  int usymBlocks = (KPAD*16*6 + 255)/256;
  binusym_kernel<<<8 + usymBlocks, 256, 0, stream>>>(types, counts, bins, U3, U2, U1, Us);
  prep2_kernel<<<NSTEP*NE + MAXBS*16, 256, 0, stream>>>(Us, W3, W2, W1, Bbuf,
                                                        x, counts, bins, xTu);
  main6_kernel<<<MAXBS*64, 256, 0, stream>>>(xTu, counts, bins, (const uint4*)Bbuf, out);
}